// Round 1
// baseline (407.062 us; speedup 1.0000x reference)
//
#include <hip/hip_runtime.h>
#include <math.h>

#define BSZ 64
#define NPT 16384
#define SEG 16
#define NFPS 256
#define MAXPTS 2048
#define NTHREADS 256
#define KPT 8  // MAXPTS / NTHREADS

__global__ __launch_bounds__(NTHREADS) void fps_part_kernel(const float* __restrict__ x,
                                                            float* __restrict__ out) {
    const int blk = blockIdx.x;          // b*16 + s
    const int b = blk >> 4;
    const int s = blk & 15;
    const int tid = threadIdx.x;
    const int lane = tid & 63;
    const int wave = tid >> 6;

    __shared__ float px[MAXPTS];
    __shared__ float py[MAXPTS];
    __shared__ float pz[MAXPTS];
    __shared__ int wcnt[4];
    __shared__ float rbv[2][4];
    __shared__ int rbi[2][4];

    // ---------------- Phase 1: stable compaction of points with label==s ----------------
    const float4* x4 = (const float4*)x + (size_t)b * NPT;
    const float fs = (float)s;
    int total = 0;  // running count, replicated in every thread (all compute same value)

    for (int mc = 0; mc < 16; ++mc) {
        float4 p[4];
        #pragma unroll
        for (int j = 0; j < 4; ++j)
            p[j] = x4[(mc * 4 + j) * NTHREADS + tid];
        #pragma unroll
        for (int j = 0; j < 4; ++j) {
            const bool pred = (p[j].w == fs);
            const unsigned long long m = __ballot(pred);
            const int lanePre = __popcll(m & ((1ull << lane) - 1ull));
            if (lane == 0) wcnt[wave] = __popcll(m);
            __syncthreads();
            const int w0 = wcnt[0], w1 = wcnt[1], w2 = wcnt[2], w3 = wcnt[3];
            int base = total;
            if (wave > 0) base += w0;
            if (wave > 1) base += w1;
            if (wave > 2) base += w2;
            if (pred) {
                const int pos = base + lanePre;
                if (pos < MAXPTS) { px[pos] = p[j].x; py[pos] = p[j].y; pz[pos] = p[j].z; }
            }
            total += w0 + w1 + w2 + w3;
            __syncthreads();  // wcnt consumed before next overwrite; also orders px writes
        }
    }

    const int count = (total < MAXPTS) ? total : MAXPTS;
    const size_t gp_base = (size_t)blk * NFPS * 3;
    const size_t mask_off = (size_t)BSZ * SEG * NFPS * 3 + (size_t)blk;

    if (count < NFPS) {
        // invalid segment: zeros + mask 0 (where(masks, sel, 0))
        for (int i = tid; i < NFPS * 3; i += NTHREADS) out[gp_base + i] = 0.0f;
        if (tid == 0) out[mask_off] = 0.0f;
        return;
    }
    if (tid == 0) out[mask_off] = 1.0f;

    // ---------------- Phase 2: FPS over compacted points ----------------
    // Each thread owns compacted indices i = tid + 256*k, cached in registers.
    float rx[KPT], ry[KPT], rz[KPT], md[KPT];
    #pragma unroll
    for (int k = 0; k < KPT; ++k) {
        const int i = tid + (k << 8);
        const bool v = (i < count);
        rx[k] = v ? px[i] : 0.0f;
        ry[k] = v ? py[i] : 0.0f;
        rz[k] = v ? pz[i] : 0.0f;
        md[k] = v ? INFINITY : -INFINITY;  // invalid slots can never win (strict >)
    }

    int cur = 0;  // compacted index 0 == first masked point == argmax(mask)
    for (int t = 0; t < NFPS; ++t) {
        const float cx = px[cur], cy = py[cur], cz = pz[cur];  // LDS broadcast (uniform addr)
        if (tid < 3) out[gp_base + (size_t)t * 3 + tid] = (tid == 0) ? cx : ((tid == 1) ? cy : cz);

        float best = -INFINITY;
        int bidx = 0x7fffffff;
        #pragma unroll
        for (int k = 0; k < KPT; ++k) {
            // Bit-exact vs reference: (dx*dx + dy*dy) + dz*dz, no FMA contraction.
            const float dx = rx[k] - cx;
            const float dy = ry[k] - cy;
            const float dz = rz[k] - cz;
            const float d = __fadd_rn(__fadd_rn(__fmul_rn(dx, dx), __fmul_rn(dy, dy)),
                                      __fmul_rn(dz, dz));
            const float m = fminf(md[k], d);
            md[k] = m;
            if (m > best) { best = m; bidx = tid + (k << 8); }  // strict > keeps lowest idx
        }

        // wave-level butterfly reduce: (max value, min index on ties) == first-max semantics
        #pragma unroll
        for (int off = 1; off < 64; off <<= 1) {
            const float ov = __shfl_xor(best, off);
            const int oi = __shfl_xor(bidx, off);
            if (ov > best || (ov == best && oi < bidx)) { best = ov; bidx = oi; }
        }

        const int buf = t & 1;  // double-buffered scratch -> one barrier per iteration
        if (lane == 0) { rbv[buf][wave] = best; rbi[buf][wave] = bidx; }
        __syncthreads();
        float bv = rbv[buf][0];
        int bi = rbi[buf][0];
        #pragma unroll
        for (int w = 1; w < 4; ++w) {
            const float ov = rbv[buf][w];
            const int oi = rbi[buf][w];
            if (ov > bv || (ov == bv && oi < bi)) { bv = ov; bi = oi; }
        }
        cur = bi;
    }
}

extern "C" void kernel_launch(void* const* d_in, const int* in_sizes, int n_in,
                              void* d_out, int out_size, void* d_ws, size_t ws_size,
                              hipStream_t stream) {
    const float* x = (const float*)d_in[0];
    float* out = (float*)d_out;
    fps_part_kernel<<<BSZ * SEG, NTHREADS, 0, stream>>>(x, out);
}

// Round 2
// 328.964 us; speedup vs baseline: 1.2374x; 1.2374x over previous
//
#include <hip/hip_runtime.h>
#include <math.h>

#define BSZ 64
#define NPT 16384
#define SEG 16
#define NFPS 256
#define MAXPTS 2048
#define NTHREADS 256
#define KPT 8  // MAXPTS / NTHREADS

__global__ __launch_bounds__(NTHREADS) void fps_part_kernel(const float* __restrict__ x,
                                                            float* __restrict__ out) {
    const int blk = blockIdx.x;          // b*16 + s
    const int b = blk >> 4;
    const int s = blk & 15;
    const int tid = threadIdx.x;
    const int lane = tid & 63;
    const int wave = tid >> 6;

    __shared__ float px[MAXPTS];
    __shared__ float py[MAXPTS];
    __shared__ float pz[MAXPTS];
    __shared__ int wcnt[4][4];                     // [wave][j]
    __shared__ unsigned long long rbk[2][4];       // double-buffered cross-wave keys

    // ---------------- Phase 1: stable compaction of points with label==s ----------------
    // 4 ballot rounds share one barrier pair (wcnt[4][4]) -> 32 barriers total, not 128.
    const float4* x4 = (const float4*)x + (size_t)b * NPT;
    const float fs = (float)s;
    const unsigned long long lanemask = (1ull << lane) - 1ull;
    int total = 0;  // running count, same value in every thread

    for (int mc = 0; mc < 16; ++mc) {
        float4 p[4];
        bool pred[4];
        int lanePre[4];
        #pragma unroll
        for (int j = 0; j < 4; ++j)
            p[j] = x4[(mc * 4 + j) * NTHREADS + tid];
        #pragma unroll
        for (int j = 0; j < 4; ++j) {
            pred[j] = (p[j].w == fs);
            const unsigned long long m = __ballot(pred[j]);
            lanePre[j] = __popcll(m & lanemask);
            if (lane == 0) wcnt[wave][j] = __popcll(m);
        }
        __syncthreads();
        #pragma unroll
        for (int j = 0; j < 4; ++j) {
            const int w0 = wcnt[0][j], w1 = wcnt[1][j], w2 = wcnt[2][j], w3 = wcnt[3][j];
            int base = total;
            if (wave > 0) base += w0;
            if (wave > 1) base += w1;
            if (wave > 2) base += w2;
            if (pred[j]) {
                const int pos = base + lanePre[j];
                if (pos < MAXPTS) { px[pos] = p[j].x; py[pos] = p[j].y; pz[pos] = p[j].z; }
            }
            total += w0 + w1 + w2 + w3;
        }
        __syncthreads();  // wcnt consumed before next round's overwrite
    }

    const int count = (total < MAXPTS) ? total : MAXPTS;
    const size_t gp_base = (size_t)blk * NFPS * 3;
    const size_t mask_off = (size_t)BSZ * SEG * NFPS * 3 + (size_t)blk;

    if (count < NFPS) {
        for (int i = tid; i < NFPS * 3; i += NTHREADS) out[gp_base + i] = 0.0f;
        if (tid == 0) out[mask_off] = 0.0f;
        return;
    }
    if (tid == 0) out[mask_off] = 1.0f;

    // ---------------- Phase 2: FPS over compacted points ----------------
    // Thread owns compacted indices i = tid + 256*k in registers. Uniform kmax guard
    // (scalar branch) skips unrolled sections past count -- ~half the slots typically.
    const int kmax = (__builtin_amdgcn_readfirstlane(count) + NTHREADS - 1) >> 8;

    float rx[KPT], ry[KPT], rz[KPT], md[KPT];
    #pragma unroll
    for (int k = 0; k < KPT; ++k) {
        const int i = tid + (k << 8);
        const bool v = (i < count);
        rx[k] = v ? px[i] : 0.0f;
        ry[k] = v ? py[i] : 0.0f;
        rz[k] = v ? pz[i] : 0.0f;
        md[k] = v ? INFINITY : -INFINITY;  // invalid slots can never win (strict >)
    }

    int cur = 0;  // compacted index 0 == argmax(mask)
    for (int t = 0; t < NFPS; ++t) {
        const float cx = px[cur], cy = py[cur], cz = pz[cur];  // uniform-addr LDS broadcast
        if (tid < 3) out[gp_base + (size_t)t * 3 + tid] = (tid == 0) ? cx : ((tid == 1) ? cy : cz);

        float best = -INFINITY;
        int bidx = 0;
        #pragma unroll
        for (int k = 0; k < KPT; ++k) {
            if (k < kmax) {  // uniform scalar branch
                // Bit-exact vs reference: (dx*dx + dy*dy) + dz*dz, no FMA contraction.
                const float dx = rx[k] - cx;
                const float dy = ry[k] - cy;
                const float dz = rz[k] - cz;
                const float d = __fadd_rn(__fadd_rn(__fmul_rn(dx, dx), __fmul_rn(dy, dy)),
                                          __fmul_rn(dz, dz));
                const float m = fminf(md[k], d);
                md[k] = m;
                if (m > best) { best = m; bidx = tid + (k << 8); }  // strict > keeps lowest idx
            }
        }

        // count >= 256 => slot k=0 valid for every thread => best is finite, >= 0.
        // f32 >= 0 orders as unsigned; pack (value, ~idx): u64 max == (max val, min idx)
        // == numpy argmax first-occurrence semantics.
        unsigned long long key =
            ((unsigned long long)__float_as_uint(best) << 32) | (unsigned)(~bidx);
        #pragma unroll
        for (int off = 1; off < 64; off <<= 1) {
            const unsigned long long ok = __shfl_xor(key, off);
            key = (ok > key) ? ok : key;
        }

        const int buf = t & 1;  // double-buffered scratch -> one barrier per iteration
        if (lane == 0) rbk[buf][wave] = key;
        __syncthreads();
        unsigned long long k01 = rbk[buf][0];
        const unsigned long long k1 = rbk[buf][1];
        if (k1 > k01) k01 = k1;
        unsigned long long k23 = rbk[buf][2];
        const unsigned long long k3 = rbk[buf][3];
        if (k3 > k23) k23 = k3;
        if (k23 > k01) k01 = k23;
        cur = (int)(~(unsigned)k01);
    }
}

extern "C" void kernel_launch(void* const* d_in, const int* in_sizes, int n_in,
                              void* d_out, int out_size, void* d_ws, size_t ws_size,
                              hipStream_t stream) {
    const float* x = (const float*)d_in[0];
    float* out = (float*)d_out;
    fps_part_kernel<<<BSZ * SEG, NTHREADS, 0, stream>>>(x, out);
}

// Round 3
// 315.417 us; speedup vs baseline: 1.2906x; 1.0430x over previous
//
#include <hip/hip_runtime.h>
#include <math.h>

#define BSZ 64
#define NPT 16384
#define SEG 16
#define NFPS 256
#define MAXPTS 2048
#define NTHREADS 256
#define KPT 8  // MAXPTS / NTHREADS

// u64 max with DPP-shifted partner; bound_ctrl=1 shifts in 0 == identity for
// non-negative keys. One step of the classic GCN wave64 reduce-to-lane63.
template <int CTRL>
__device__ __forceinline__ unsigned long long dpp_max_u64(unsigned long long k) {
    const int lo = __builtin_amdgcn_update_dpp(0, (int)(unsigned)k, CTRL, 0xf, 0xf, true);
    const int hi = __builtin_amdgcn_update_dpp(0, (int)(unsigned)(k >> 32), CTRL, 0xf, 0xf, true);
    const unsigned long long ok = ((unsigned long long)(unsigned)hi << 32) | (unsigned)lo;
    return ok > k ? ok : k;
}

__global__ __launch_bounds__(NTHREADS) void fps_part_kernel(const float* __restrict__ x,
                                                            float* __restrict__ out) {
    const int blk = blockIdx.x;          // b*16 + s
    const int b = blk >> 4;
    const int s = blk & 15;
    const int tid = threadIdx.x;
    const int lane = tid & 63;
    const int wave = tid >> 6;

    __shared__ float4 pts[MAXPTS];                 // xyz + (ignored) w
    __shared__ int wcnt[4][4];                     // [wave][j]
    __shared__ unsigned long long rbk[2][4];       // double-buffered cross-wave keys

    // ---------------- Phase 1: stable compaction of points with label==s ----------------
    const float4* x4 = (const float4*)x + (size_t)b * NPT;
    const float fs = (float)s;
    const unsigned long long lanemask = (1ull << lane) - 1ull;
    int total = 0;  // running count, same value in every thread

    for (int mc = 0; mc < 16; ++mc) {
        float4 p[4];
        bool pred[4];
        int lanePre[4];
        #pragma unroll
        for (int j = 0; j < 4; ++j)
            p[j] = x4[(mc * 4 + j) * NTHREADS + tid];
        #pragma unroll
        for (int j = 0; j < 4; ++j) {
            pred[j] = (p[j].w == fs);
            const unsigned long long m = __ballot(pred[j]);
            lanePre[j] = __popcll(m & lanemask);
            if (lane == 0) wcnt[wave][j] = __popcll(m);
        }
        __syncthreads();
        #pragma unroll
        for (int j = 0; j < 4; ++j) {
            const int w0 = wcnt[0][j], w1 = wcnt[1][j], w2 = wcnt[2][j], w3 = wcnt[3][j];
            int base = total;
            if (wave > 0) base += w0;
            if (wave > 1) base += w1;
            if (wave > 2) base += w2;
            if (pred[j]) {
                const int pos = base + lanePre[j];
                if (pos < MAXPTS) pts[pos] = p[j];   // one ds_write_b128
            }
            total += w0 + w1 + w2 + w3;
        }
        __syncthreads();  // wcnt consumed before next round's overwrite
    }

    const int count = (total < MAXPTS) ? total : MAXPTS;
    const size_t gp_base = (size_t)blk * NFPS * 3;
    const size_t mask_off = (size_t)BSZ * SEG * NFPS * 3 + (size_t)blk;

    if (count < NFPS) {
        for (int i = tid; i < NFPS * 3; i += NTHREADS) out[gp_base + i] = 0.0f;
        if (tid == 0) out[mask_off] = 0.0f;
        return;
    }
    if (tid == 0) out[mask_off] = 1.0f;

    // ---------------- Phase 2: FPS over compacted points ----------------
    const int kmax = (__builtin_amdgcn_readfirstlane(count) + NTHREADS - 1) >> 8;

    float rx[KPT], ry[KPT], rz[KPT], md[KPT];
    #pragma unroll
    for (int k = 0; k < KPT; ++k) {
        const int i = tid + (k << 8);
        const bool v = (i < count);
        const float4 q = pts[v ? i : 0];
        rx[k] = q.x; ry[k] = q.y; rz[k] = q.z;
        md[k] = v ? INFINITY : -INFINITY;  // invalid slots can never win (strict >)
    }

    int cur = 0;  // compacted index 0 == argmax(mask)
    for (int t = 0; t < NFPS; ++t) {
        const float4 c = pts[cur];         // single ds_read_b128 broadcast
        const float cx = c.x, cy = c.y, cz = c.z;
        if (tid < 3) out[gp_base + (size_t)t * 3 + tid] = (tid == 0) ? cx : ((tid == 1) ? cy : cz);

        float best = -INFINITY;
        int bidx = 0;
        #pragma unroll
        for (int k = 0; k < KPT; ++k) {
            if (k < kmax) {  // uniform scalar branch
                // Bit-exact vs reference: (dx*dx + dy*dy) + dz*dz, no FMA contraction.
                const float dx = rx[k] - cx;
                const float dy = ry[k] - cy;
                const float dz = rz[k] - cz;
                const float d = __fadd_rn(__fadd_rn(__fmul_rn(dx, dx), __fmul_rn(dy, dy)),
                                          __fmul_rn(dz, dz));
                const float m = fminf(md[k], d);
                md[k] = m;
                if (m > best) { best = m; bidx = tid + (k << 8); }  // strict > keeps lowest idx
            }
        }

        // count >= 256 => every thread's k=0 slot valid => best finite, >= 0.
        // key = (value_bits << 32) | ~idx ; u64 max == (max val, min idx) == np.argmax.
        unsigned long long key =
            ((unsigned long long)__float_as_uint(best) << 32) | (unsigned)(~bidx);

        // DPP reduce-to-lane63 (full-rate VALU, no LDS-unit latency).
        key = dpp_max_u64<0x111>(key);  // row_shr:1
        key = dpp_max_u64<0x112>(key);  // row_shr:2
        key = dpp_max_u64<0x114>(key);  // row_shr:4
        key = dpp_max_u64<0x118>(key);  // row_shr:8
        key = dpp_max_u64<0x142>(key);  // row_bcast:15
        key = dpp_max_u64<0x143>(key);  // row_bcast:31

        const int buf = t & 1;  // double-buffered scratch -> one barrier per iteration
        if (lane == 63) rbk[buf][wave] = key;
        __syncthreads();
        unsigned long long k01 = rbk[buf][0];
        const unsigned long long k1 = rbk[buf][1];
        if (k1 > k01) k01 = k1;
        unsigned long long k23 = rbk[buf][2];
        const unsigned long long k3 = rbk[buf][3];
        if (k3 > k23) k23 = k3;
        if (k23 > k01) k01 = k23;
        cur = (int)(~(unsigned)k01);
    }
}

extern "C" void kernel_launch(void* const* d_in, const int* in_sizes, int n_in,
                              void* d_out, int out_size, void* d_ws, size_t ws_size,
                              hipStream_t stream) {
    const float* x = (const float*)d_in[0];
    float* out = (float*)d_out;
    fps_part_kernel<<<BSZ * SEG, NTHREADS, 0, stream>>>(x, out);
}